// Round 8
// baseline (160.221 us; speedup 1.0000x reference)
//
#include <hip/hip_runtime.h>

#define NTOK 16384
#define DIM  512
#define NEXP 8
#define NPAIR 64             // sparse pair buckets: key = lo*8+hi (28 active)
#define PCAP 8192            // per-pair capacity (mean ~585 here; huge headroom)

#define BM 128
#define BN 128
#define BK 32                // UNPADDED: required for global_load_lds lane-contiguous dest

typedef __bf16 bf16x8 __attribute__((ext_vector_type(8)));
typedef __bf16 bf16x4 __attribute__((ext_vector_type(4)));
typedef float  f32x4  __attribute__((ext_vector_type(4)));

// async global->LDS 16B per lane. LDS dest MUST be wave-uniform base + lane*16.
__device__ __forceinline__ void async_cp16(const void* g, void* l) {
    __builtin_amdgcn_global_load_lds((const __attribute__((address_space(1))) void*)g,
                                     (__attribute__((address_space(3))) void*)l, 16, 0, 0);
}

// ---------------- K1: fused prep ----------------
// blocks [0,2048)    : W [E][k][o] f32 -> Wt tiled [e][kt][o][32] bf16 (transpose+convert)
// blocks [2048,2304) : x f32 -> xb bf16
// blocks [2304,2368) : pair routing (counting sort of TOKENS into 64 pair buckets) + loss slot
__global__ __launch_bounds__(256) void k_prep(const float* __restrict__ W,
                                              __bf16* __restrict__ Wt,
                                              const float* __restrict__ x,
                                              __bf16* __restrict__ xb,
                                              const int* __restrict__ indices,
                                              const float* __restrict__ probs,
                                              int* __restrict__ cnt,
                                              int* __restrict__ tok_arr,
                                              float* __restrict__ plo_arr,
                                              float* __restrict__ phi_arr,
                                              float* __restrict__ out) {
    int b = blockIdx.x, tid = threadIdx.x;
    if (b < 2048) {
        __shared__ __bf16 tile[32][34];             // +2 pad breaks transpose bank conflicts
        int e = b >> 8, rem = b & 255;
        int o0 = (rem >> 4) * 32, k0 = (rem & 15) * 32;
        const float* Wsrc = W + ((size_t)e * DIM + k0) * DIM + o0;
        for (int i = tid; i < 1024; i += 256) {
            int kk = i >> 5, oo = i & 31;           // consecutive tid -> consecutive oo: coalesced
            tile[oo][kk] = (__bf16)Wsrc[(size_t)kk * DIM + oo];
        }
        __syncthreads();
        __bf16* dst = Wt + ((size_t)(e * 16 + (k0 >> 5)) * DIM + o0) * 32;
        for (int i = tid; i < 1024; i += 256) {
            int oo = i >> 5, kk = i & 31;           // row o0+oo, 32 k-elems contiguous
            dst[oo * 32 + kk] = tile[oo][kk];
        }
    } else if (b < 2304) {
        int base = (b - 2048) * 256 + tid;          // 2,097,152 float4 over 256 blocks
        const float4* src = (const float4*)x;
        #pragma unroll
        for (int it = 0; it < 32; ++it) {
            int i = base + it * 65536;
            float4 v = src[i];
            bf16x4 h; h[0] = (__bf16)v.x; h[1] = (__bf16)v.y; h[2] = (__bf16)v.z; h[3] = (__bf16)v.w;
            *(bf16x4*)&xb[(size_t)i * 4] = h;
        }
    } else {
        __shared__ int lcnt[NPAIR], lbase[NPAIR];
        int t = (b - 2304) * 256 + tid;             // token id; 64 blocks cover 16384 tokens
        if (tid < NPAIR) lcnt[tid] = 0;
        __syncthreads();
        int   e0 = indices[2 * t], e1 = indices[2 * t + 1];
        float p0 = probs[2 * t],   p1 = probs[2 * t + 1];
        int lo = min(e0, e1), hi = max(e0, e1);
        float plo = (e0 < e1) ? p0 : p1;
        float phi = (e0 < e1) ? p1 : p0;
        int key = lo * 8 + hi;
        int lr = atomicAdd(&lcnt[key], 1);
        __syncthreads();
        if (tid < NPAIR) lbase[tid] = atomicAdd(&cnt[tid], lcnt[tid]);
        __syncthreads();
        int pos = lbase[key] + lr;
        if (pos < PCAP) {                           // memory-safety clamp (never hit at this dist)
            int q = key * PCAP + pos;
            tok_arr[q] = t; plo_arr[q] = plo; phi_arr[q] = phi;
        }
        if (b == 2304 && tid == 0) out[NTOK * DIM] = 0.0f;   // total_loss
    }
}

// ---------------- K2: pair-grouped GEMM, INTERLEAVED dual accumulators ----------------
// Single K-sweep (16 stages): each stage stages A once + B_lo + B_hi, runs both experts'
// MFMAs into separate accumulators. out = pl*acc_lo + ph*acc_hi + pl*b_lo + ph*b_hi.
// grid 640 = 160 m-slots x 4 n-tiles; 4 n-tiles of an m-slot share blockIdx%8 -> same XCD.
// Each block owns its (rows, col-slice) exclusively: plain fp32 stores, no atomics.
__global__ __launch_bounds__(256) void k_gemm(const __bf16* __restrict__ xb,
                                              const __bf16* __restrict__ Wt,
                                              const float* __restrict__ bias,
                                              const int* __restrict__ tok_arr,
                                              const float* __restrict__ plo_arr,
                                              const float* __restrict__ phi_arr,
                                              const int* __restrict__ cnt,
                                              float* __restrict__ out) {
    int p = blockIdx.x;
    int m_slot = (p >> 5) * 8 + (p & 7);            // [0,160)
    int nt = (p >> 3) & 3;
    int key = -1, m_t = 0, count = 0, total = 0;
    for (int i = 0; i < NPAIR; ++i) {               // uniform scalar prefix decode
        int c = cnt[i];
        int tl = (c + BM - 1) >> 7;
        if (key < 0 && m_slot < total + tl) { key = i; m_t = m_slot - total; count = c; }
        total += tl;
    }
    if (key < 0) return;                            // padding slots (total <= 156)
    if (count > PCAP) count = PCAP;
    int lo = key >> 3, hi = key & 7;
    int m0 = m_t * BM, n0 = nt * BN, tid = threadIdx.x;

    // A dbuf @0/8K, Blo dbuf @16K/24K, Bhi dbuf @32K/40K
    __shared__ __attribute__((aligned(16))) char smem[49152];
    __shared__ int   sTok[BM];
    __shared__ float sPlo[BM], sPhi[BM];

    if (tid < BM) {
        int g = m0 + tid;
        int tk = 0; float a = 0.f, h = 0.f;
        if (g < count) {
            int q = key * PCAP + g;
            tk = tok_arr[q]; a = plo_arr[q]; h = phi_arr[q];
        }
        sTok[tid] = tk;                             // invalid rows alias token 0 (loads safe, store skipped)
        sPlo[tid] = a; sPhi[tid] = h;
    }
    __syncthreads();

    int wid  = tid >> 6, lane = tid & 63;
    int quad = lane >> 4, rr  = lane & 15;
    int wm = (wid >> 1) * 64, wn = (wid & 1) * 64;  // 2x2 waves over 128x128

    // staging duty: chunks tid / tid+256; row r=c>>2, logical chunk q=c&3.
    // XOR swizzle: this thread FETCHES logical chunk (q ^ (r&3)) so slot q holds it.
    int rA0 = tid >> 2;
    int swz = ((tid & 3) ^ (rA0 & 3)) << 3;         // same for chunk tid+256 (r+64 keeps r&3)
    const __bf16* gA0 = xb + (size_t)sTok[rA0]      * DIM + swz;
    const __bf16* gA1 = xb + (size_t)sTok[rA0 + 64] * DIM + swz;
    // B staging from tiled Wt: slab base + swizzled chunk offset
    size_t bOff = (size_t)((rA0 * 4 + ((tid & 3) ^ (rA0 & 3))) * 8);
    const __bf16* gBlo = Wt + ((size_t)(lo * 16) * DIM + n0) * 32 + bOff;
    const __bf16* gBhi = Wt + ((size_t)(hi * 16) * DIM + n0) * 32 + bOff;

    f32x4 accL[4][4] = {};
    f32x4 accH[4][4] = {};

    // preload kt=0 into buffer 0
    async_cp16(gA0,         smem + tid * 16);
    async_cp16(gA1,         smem + tid * 16 + 4096);
    async_cp16(gBlo,        smem + 16384 + tid * 16);
    async_cp16(gBlo + 2048, smem + 16384 + tid * 16 + 4096);
    async_cp16(gBhi,        smem + 32768 + tid * 16);
    async_cp16(gBhi + 2048, smem + 32768 + tid * 16 + 4096);

    #pragma unroll 2
    for (int kt = 0; kt < 16; ++kt) {
        int cur = kt & 1;
        __syncthreads();                            // drains vmcnt(0): buf[cur] ready
        if (kt < 15) {                              // prefetch kt+1 into other buffer
            int ka = (kt + 1) * BK;
            size_t wOff = (size_t)(kt + 1) * DIM * 32;
            char* dA  = smem +         ((kt + 1) & 1) * 8192;
            char* dBl = smem + 16384 + ((kt + 1) & 1) * 8192;
            char* dBh = smem + 32768 + ((kt + 1) & 1) * 8192;
            async_cp16(gA0 + ka,          dA  + tid * 16);
            async_cp16(gA1 + ka,          dA  + tid * 16 + 4096);
            async_cp16(gBlo + wOff,       dBl + tid * 16);
            async_cp16(gBlo + wOff + 2048, dBl + tid * 16 + 4096);
            async_cp16(gBhi + wOff,       dBh + tid * 16);
            async_cp16(gBhi + wOff + 2048, dBh + tid * 16 + 4096);
        }
        const __bf16* sA  = (const __bf16*)(smem +         cur * 8192);
        const __bf16* sBl = (const __bf16*)(smem + 16384 + cur * 8192);
        const __bf16* sBh = (const __bf16*)(smem + 32768 + cur * 8192);
        int csw = (quad ^ (rr & 3)) * 8;            // swizzled k-chunk slot (row&3 == rr&3)
        bf16x8 af[4], bl[4], bh[4];
        #pragma unroll
        for (int i = 0; i < 4; ++i)
            af[i] = *(bf16x8*)&sA[(wm + i * 16 + rr) * BK + csw];    // A[m=rr][k=quad*8+j]
        #pragma unroll
        for (int j = 0; j < 4; ++j) {
            bl[j] = *(bf16x8*)&sBl[(wn + j * 16 + rr) * BK + csw];   // B[n=rr][k=quad*8+j]
            bh[j] = *(bf16x8*)&sBh[(wn + j * 16 + rr) * BK + csw];
        }
        #pragma unroll
        for (int i = 0; i < 4; ++i)
            #pragma unroll
            for (int j = 0; j < 4; ++j) {
                accL[i][j] = __builtin_amdgcn_mfma_f32_16x16x32_bf16(af[i], bl[j], accL[i][j], 0, 0, 0);
                accH[i][j] = __builtin_amdgcn_mfma_f32_16x16x32_bf16(af[i], bh[j], accH[i][j], 0, 0, 0);
            }
    }

    // epilogue: C/D layout col=lane&15, row=quad*4+reg.
    // out[tok][col] = pl*accL + ph*accH + pl*b_lo[col] + ph*b_hi[col]  (exclusive owner, plain stores)
    float blo[4], bhi[4];
    #pragma unroll
    for (int j = 0; j < 4; ++j) {
        blo[j] = bias[lo * DIM + n0 + wn + j * 16 + rr];
        bhi[j] = bias[hi * DIM + n0 + wn + j * 16 + rr];
    }
    #pragma unroll
    for (int i = 0; i < 4; ++i) {
        #pragma unroll
        for (int reg = 0; reg < 4; ++reg) {
            int row = wm + i * 16 + quad * 4 + reg;
            int g = m0 + row;
            if (g >= count) continue;
            int   tk = sTok[row];
            float pl = sPlo[row], ph = sPhi[row];
            float* dst = out + (size_t)tk * DIM + n0 + wn + rr;
            #pragma unroll
            for (int j = 0; j < 4; ++j)
                dst[j * 16] = accL[i][j][reg] * pl + accH[i][j][reg] * ph + pl * blo[j] + ph * bhi[j];
        }
    }
}

extern "C" void kernel_launch(void* const* d_in, const int* in_sizes, int n_in,
                              void* d_out, int out_size, void* d_ws, size_t ws_size,
                              hipStream_t stream) {
    const float* x    = (const float*)d_in[0];   // [N, D]
    const float* prob = (const float*)d_in[1];   // [N, K]
    const int*   idx  = (const int*)d_in[2];     // [N, K]
    const float* W    = (const float*)d_in[3];   // [E, D, D]
    const float* b    = (const float*)d_in[4];   // [E, D]
    float* out = (float*)d_out;                  // [N*D + 1]

    // workspace:
    //   Wt      : E*D*D bf16 (K-tiled [e][kt][o][32]) =  4,194,304 B
    //   xb      : N*D bf16                            = 16,777,216 B
    //   cnt     : 64 int (256 B reserved)
    //   tok_arr : 64*PCAP int                         =  2,097,152 B
    //   plo_arr : 64*PCAP float                       =  2,097,152 B
    //   phi_arr : 64*PCAP float                       =  2,097,152 B     total ~27.3 MB
    char* ws = (char*)d_ws;
    __bf16* Wt      = (__bf16*)ws;
    __bf16* xb      = (__bf16*)(ws + 4194304);
    int*    cnt     = (int*)   (ws + 4194304 + 16777216);
    int*    tok_arr = (int*)   (ws + 4194304 + 16777216 + 256);
    float*  plo_arr = (float*) (ws + 4194304 + 16777216 + 256 + 2097152);
    float*  phi_arr = (float*) (ws + 4194304 + 16777216 + 256 + 2 * 2097152);

    (void)hipMemsetAsync(cnt, 0, NPAIR * sizeof(int), stream);
    hipLaunchKernelGGL(k_prep, dim3(2368), dim3(256), 0, stream,
                       W, Wt, x, xb, idx, prob, cnt, tok_arr, plo_arr, phi_arr, out);
    hipLaunchKernelGGL(k_gemm, dim3(640), dim3(256), 0, stream,
                       xb, Wt, b, tok_arr, plo_arr, phi_arr, cnt, out);
}

// Round 9
// 139.034 us; speedup vs baseline: 1.1524x; 1.1524x over previous
//
#include <hip/hip_runtime.h>

#define NTOK 16384
#define DIM  512
#define NEXP 8
#define NPAIR 64             // sparse pair buckets: key = lo*8+hi (28 active)
#define PCAP 8192            // per-pair capacity (mean ~585 here; huge headroom)

#define BM 128
#define BN 64                // small n-tile: keeps dual-acc at 64 AGPR, doubles grid
#define BK 32                // UNPADDED: required for global_load_lds lane-contiguous dest

typedef __bf16 bf16x8 __attribute__((ext_vector_type(8)));
typedef __bf16 bf16x4 __attribute__((ext_vector_type(4)));
typedef float  f32x4  __attribute__((ext_vector_type(4)));

// async global->LDS 16B per lane. LDS dest MUST be wave-uniform base + lane*16.
__device__ __forceinline__ void async_cp16(const void* g, void* l) {
    __builtin_amdgcn_global_load_lds((const __attribute__((address_space(1))) void*)g,
                                     (__attribute__((address_space(3))) void*)l, 16, 0, 0);
}

// ---------------- K1: fused prep ----------------
// blocks [0,2048)    : W [E][k][o] f32 -> Wt tiled [e][kt][o][32] bf16 (transpose+convert)
// blocks [2048,2304) : x f32 -> xb bf16
// blocks [2304,2368) : pair routing (counting sort of TOKENS into 64 pair buckets) + loss slot
__global__ __launch_bounds__(256) void k_prep(const float* __restrict__ W,
                                              __bf16* __restrict__ Wt,
                                              const float* __restrict__ x,
                                              __bf16* __restrict__ xb,
                                              const int* __restrict__ indices,
                                              const float* __restrict__ probs,
                                              int* __restrict__ cnt,
                                              int* __restrict__ tok_arr,
                                              float* __restrict__ plo_arr,
                                              float* __restrict__ phi_arr,
                                              float* __restrict__ out) {
    int b = blockIdx.x, tid = threadIdx.x;
    if (b < 2048) {
        __shared__ __bf16 tile[32][34];             // +2 pad breaks transpose bank conflicts
        int e = b >> 8, rem = b & 255;
        int o0 = (rem >> 4) * 32, k0 = (rem & 15) * 32;
        const float* Wsrc = W + ((size_t)e * DIM + k0) * DIM + o0;
        for (int i = tid; i < 1024; i += 256) {
            int kk = i >> 5, oo = i & 31;           // consecutive tid -> consecutive oo: coalesced
            tile[oo][kk] = (__bf16)Wsrc[(size_t)kk * DIM + oo];
        }
        __syncthreads();
        __bf16* dst = Wt + ((size_t)(e * 16 + (k0 >> 5)) * DIM + o0) * 32;
        for (int i = tid; i < 1024; i += 256) {
            int oo = i >> 5, kk = i & 31;           // row o0+oo, 32 k-elems contiguous
            dst[oo * 32 + kk] = tile[oo][kk];
        }
    } else if (b < 2304) {
        int base = (b - 2048) * 256 + tid;          // 2,097,152 float4 over 256 blocks
        const float4* src = (const float4*)x;
        #pragma unroll
        for (int it = 0; it < 32; ++it) {
            int i = base + it * 65536;
            float4 v = src[i];
            bf16x4 h; h[0] = (__bf16)v.x; h[1] = (__bf16)v.y; h[2] = (__bf16)v.z; h[3] = (__bf16)v.w;
            *(bf16x4*)&xb[(size_t)i * 4] = h;
        }
    } else {
        __shared__ int lcnt[NPAIR], lbase[NPAIR];
        int t = (b - 2304) * 256 + tid;             // token id; 64 blocks cover 16384 tokens
        if (tid < NPAIR) lcnt[tid] = 0;
        __syncthreads();
        int   e0 = indices[2 * t], e1 = indices[2 * t + 1];
        float p0 = probs[2 * t],   p1 = probs[2 * t + 1];
        int lo = min(e0, e1), hi = max(e0, e1);
        float plo = (e0 < e1) ? p0 : p1;
        float phi = (e0 < e1) ? p1 : p0;
        int key = lo * 8 + hi;
        int lr = atomicAdd(&lcnt[key], 1);
        __syncthreads();
        if (tid < NPAIR) lbase[tid] = atomicAdd(&cnt[tid], lcnt[tid]);
        __syncthreads();
        int pos = lbase[key] + lr;
        if (pos < PCAP) {                           // memory-safety clamp (never hit at this dist)
            int q = key * PCAP + pos;
            tok_arr[q] = t; plo_arr[q] = plo; phi_arr[q] = phi;
        }
        if (b == 2304 && tid == 0) out[NTOK * DIM] = 0.0f;   // total_loss
    }
}

// ---------------- K2: pair-grouped GEMM, interleaved dual acc, 128x64 tiles ----------------
// Single K-sweep (16 stages): stage A once + B_lo + B_hi, both experts' MFMAs per stage.
// out = pl*acc_lo + ph*acc_hi + pl*b_lo + ph*b_hi.  Per wave: 64x32 per expert -> 64 AGPR.
// grid 1280 = 160 m-slots x 8 n-tiles; the 8 n-tiles of an m-slot share blockIdx%8 -> same
// XCD (A rows L2-fetched once per XCD). Exclusive (rows, col-slice) owner: plain stores.
__global__ __launch_bounds__(256) void k_gemm(const __bf16* __restrict__ xb,
                                              const __bf16* __restrict__ Wt,
                                              const float* __restrict__ bias,
                                              const int* __restrict__ tok_arr,
                                              const float* __restrict__ plo_arr,
                                              const float* __restrict__ phi_arr,
                                              const int* __restrict__ cnt,
                                              float* __restrict__ out) {
    int p = blockIdx.x;
    int r = p & 7;
    int nt = (p >> 3) & 7;
    int m_slot = (p >> 6) * 8 + r;                  // [0,160)
    int key = -1, m_t = 0, count = 0, total = 0;
    for (int i = 0; i < NPAIR; ++i) {               // uniform scalar prefix decode
        int c = cnt[i];
        int tl = (c + BM - 1) >> 7;
        if (key < 0 && m_slot < total + tl) { key = i; m_t = m_slot - total; count = c; }
        total += tl;
    }
    if (key < 0) return;                            // padding slots (total <= 156)
    if (count > PCAP) count = PCAP;
    int lo = key >> 3, hi = key & 7;
    int m0 = m_t * BM, n0 = nt * BN, tid = threadIdx.x;

    // A dbuf @0/8K (8KB each), Bl dbuf @16K/20K (4KB each), Bh dbuf @24K/28K
    __shared__ __attribute__((aligned(16))) char smem[32768];
    __shared__ int   sTok[BM];
    __shared__ float sPlo[BM], sPhi[BM];

    if (tid < BM) {
        int g = m0 + tid;
        int tk = 0; float a = 0.f, h = 0.f;
        if (g < count) {
            int q = key * PCAP + g;
            tk = tok_arr[q]; a = plo_arr[q]; h = phi_arr[q];
        }
        sTok[tid] = tk;                             // invalid rows alias token 0 (loads safe, store skipped)
        sPlo[tid] = a; sPhi[tid] = h;
    }
    __syncthreads();

    int wid  = tid >> 6, lane = tid & 63;
    int quad = lane >> 4, rr  = lane & 15;
    int wm = (wid >> 1) * 64, wn = (wid & 1) * 32;  // 2x2 waves over 128x64

    // A staging duty: chunks tid / tid+256; row rc=c>>2, chunk q=c&3, XOR-swizzled source.
    int rA0 = tid >> 2;
    int swz = ((tid & 3) ^ (rA0 & 3)) << 3;         // rows rA0 and rA0+64 share rA0&3
    const __bf16* gA0 = xb + (size_t)sTok[rA0]      * DIM + swz;
    const __bf16* gA1 = xb + (size_t)sTok[rA0 + 64] * DIM + swz;
    // B staging: 64 rows x 32k = 4KB = 256 chunks -> 1 chunk/thread per expert
    size_t bOff = (size_t)((rA0 * 4 + ((tid & 3) ^ (rA0 & 3))) * 8);
    const __bf16* gBlo = Wt + ((size_t)(lo * 16) * DIM + n0) * 32 + bOff;
    const __bf16* gBhi = Wt + ((size_t)(hi * 16) * DIM + n0) * 32 + bOff;

    f32x4 accL[4][2] = {};
    f32x4 accH[4][2] = {};

    // preload kt=0 into buffer 0
    async_cp16(gA0,  smem + tid * 16);
    async_cp16(gA1,  smem + tid * 16 + 4096);
    async_cp16(gBlo, smem + 16384 + tid * 16);
    async_cp16(gBhi, smem + 24576 + tid * 16);

    #pragma unroll 2
    for (int kt = 0; kt < 16; ++kt) {
        int cur = kt & 1;
        __syncthreads();                            // drains vmcnt(0): buf[cur] ready
        if (kt < 15) {                              // prefetch kt+1 into other buffer
            int ka = (kt + 1) * BK;
            size_t wOff = (size_t)(kt + 1) * DIM * 32;
            int nx = (kt + 1) & 1;
            async_cp16(gA0 + ka,    smem + nx * 8192 + tid * 16);
            async_cp16(gA1 + ka,    smem + nx * 8192 + tid * 16 + 4096);
            async_cp16(gBlo + wOff, smem + 16384 + nx * 4096 + tid * 16);
            async_cp16(gBhi + wOff, smem + 24576 + nx * 4096 + tid * 16);
        }
        const __bf16* sA  = (const __bf16*)(smem +         cur * 8192);
        const __bf16* sBl = (const __bf16*)(smem + 16384 + cur * 4096);
        const __bf16* sBh = (const __bf16*)(smem + 24576 + cur * 4096);
        int csw = (quad ^ (rr & 3)) * 8;            // swizzled k-chunk slot
        bf16x8 af[4], bl[2], bh[2];
        #pragma unroll
        for (int i = 0; i < 4; ++i)
            af[i] = *(bf16x8*)&sA[(wm + i * 16 + rr) * BK + csw];    // A[m=rr][k=quad*8+j]
        #pragma unroll
        for (int j = 0; j < 2; ++j) {
            bl[j] = *(bf16x8*)&sBl[(wn + j * 16 + rr) * BK + csw];   // B[n=rr][k=quad*8+j]
            bh[j] = *(bf16x8*)&sBh[(wn + j * 16 + rr) * BK + csw];
        }
        #pragma unroll
        for (int i = 0; i < 4; ++i)
            #pragma unroll
            for (int j = 0; j < 2; ++j) {
                accL[i][j] = __builtin_amdgcn_mfma_f32_16x16x32_bf16(af[i], bl[j], accL[i][j], 0, 0, 0);
                accH[i][j] = __builtin_amdgcn_mfma_f32_16x16x32_bf16(af[i], bh[j], accH[i][j], 0, 0, 0);
            }
    }

    // epilogue: C/D layout col=lane&15, row=quad*4+reg.
    // out[tok][col] = pl*accL + ph*accH + pl*b_lo[col] + ph*b_hi[col]  (exclusive owner)
    float blo[2], bhi[2];
    #pragma unroll
    for (int j = 0; j < 2; ++j) {
        blo[j] = bias[lo * DIM + n0 + wn + j * 16 + rr];
        bhi[j] = bias[hi * DIM + n0 + wn + j * 16 + rr];
    }
    #pragma unroll
    for (int i = 0; i < 4; ++i) {
        #pragma unroll
        for (int reg = 0; reg < 4; ++reg) {
            int row = wm + i * 16 + quad * 4 + reg;
            int g = m0 + row;
            if (g >= count) continue;
            int   tk = sTok[row];
            float pl = sPlo[row], ph = sPhi[row];
            float* dst = out + (size_t)tk * DIM + n0 + wn + rr;
            #pragma unroll
            for (int j = 0; j < 2; ++j)
                dst[j * 16] = accL[i][j][reg] * pl + accH[i][j][reg] * ph + pl * blo[j] + ph * bhi[j];
        }
    }
}

extern "C" void kernel_launch(void* const* d_in, const int* in_sizes, int n_in,
                              void* d_out, int out_size, void* d_ws, size_t ws_size,
                              hipStream_t stream) {
    const float* x    = (const float*)d_in[0];   // [N, D]
    const float* prob = (const float*)d_in[1];   // [N, K]
    const int*   idx  = (const int*)d_in[2];     // [N, K]
    const float* W    = (const float*)d_in[3];   // [E, D, D]
    const float* b    = (const float*)d_in[4];   // [E, D]
    float* out = (float*)d_out;                  // [N*D + 1]

    // workspace:
    //   Wt      : E*D*D bf16 (K-tiled [e][kt][o][32]) =  4,194,304 B
    //   xb      : N*D bf16                            = 16,777,216 B
    //   cnt     : 64 int (256 B reserved)
    //   tok_arr : 64*PCAP int                         =  2,097,152 B
    //   plo_arr : 64*PCAP float                       =  2,097,152 B
    //   phi_arr : 64*PCAP float                       =  2,097,152 B     total ~27.3 MB
    char* ws = (char*)d_ws;
    __bf16* Wt      = (__bf16*)ws;
    __bf16* xb      = (__bf16*)(ws + 4194304);
    int*    cnt     = (int*)   (ws + 4194304 + 16777216);
    int*    tok_arr = (int*)   (ws + 4194304 + 16777216 + 256);
    float*  plo_arr = (float*) (ws + 4194304 + 16777216 + 256 + 2097152);
    float*  phi_arr = (float*) (ws + 4194304 + 16777216 + 256 + 2 * 2097152);

    (void)hipMemsetAsync(cnt, 0, NPAIR * sizeof(int), stream);
    hipLaunchKernelGGL(k_prep, dim3(2368), dim3(256), 0, stream,
                       W, Wt, x, xb, idx, prob, cnt, tok_arr, plo_arr, phi_arr, out);
    hipLaunchKernelGGL(k_gemm, dim3(1280), dim3(256), 0, stream,
                       xb, Wt, b, tok_arr, plo_arr, phi_arr, cnt, out);
}